// Round 2
// baseline (783.297 us; speedup 1.0000x reference)
//
#include <hip/hip_runtime.h>

// Problem constants (fixed shapes from reference)
#define BB     4
#define CVC    16
#define CPC    16
#define CCC    32          // CV + CP
#define XD     256
#define YD     256
#define ZD     32
#define NVX    100000
#define NORIG  131072
#define NSLOT  50
#define DD     256
#define XYZ    (XD*YD*ZD)            // 2097152
#define BN     ((size_t)BB*NORIG)    // 524288 output columns

// ---- init: inv = -1 everywhere, stats = 0 (ws is poisoned 0xAA each call) ----
__global__ __launch_bounds__(256) void fill_kernel(int* __restrict__ inv,
                                                   float* __restrict__ stats){
  int i = blockIdx.x*256 + threadIdx.x;
  if (i < (int)BN) inv[i] = -1;
  if (i < 32) stats[i] = 0.f;
}

// ---- inverse scatter index: inv[b][orig] = point n (point_idxes unique/batch) ----
__global__ __launch_bounds__(256) void scatter_kernel(const int* __restrict__ pidx,
                                                      int* __restrict__ inv){
  int t = blockIdx.x*256 + threadIdx.x;
  if (t < BB*NVX){
    int b = t / NVX;
    int n = t - b*NVX;
    inv[b*NORIG + pidx[t]] = n;
  }
}

// ---- slot MLP stage 1: h = W1 @ slot^T + b1, plus GroupNorm partial stats ----
// grid (NSLOT, BB), 256 threads; thread d computes h[b, d, s]
__global__ __launch_bounds__(256) void mlp1_kernel(
    const float* __restrict__ slot, const float* __restrict__ W1,
    const float* __restrict__ b1, float* __restrict__ ws_h,
    float* __restrict__ stats){
  int s = blockIdx.x, b = blockIdx.y, d = threadIdx.x;
  __shared__ float sv[DD];
  sv[d] = slot[((size_t)b*NSLOT + s)*DD + d];
  __syncthreads();
  const float4* w1q = (const float4*)(W1 + (size_t)d*DD);
  float acc = b1[d];
  #pragma unroll
  for (int q = 0; q < 64; q++){
    float4 w = w1q[q];
    const float* sp = &sv[q*4];
    acc = fmaf(w.x, sp[0], acc);
    acc = fmaf(w.y, sp[1], acc);
    acc = fmaf(w.z, sp[2], acc);
    acc = fmaf(w.w, sp[3], acc);
  }
  ws_h[((size_t)b*NSLOT + s)*DD + d] = acc;
  // GroupNorm(4): group g = d>>6 == wave id; partial sums over this slot column
  float s1 = acc, s2 = acc*acc;
  #pragma unroll
  for (int off = 32; off > 0; off >>= 1){
    s1 += __shfl_down(s1, off, 64);
    s2 += __shfl_down(s2, off, 64);
  }
  if ((d & 63) == 0){
    int g = d >> 6;
    atomicAdd(&stats[(b*4+g)*2+0], s1);
    atomicAdd(&stats[(b*4+g)*2+1], s2);
  }
}

// ---- slot MLP stage 2: GN+ReLU, slot_proj = W2@h + b2, l2norm over CC, *20 ----
// grid (NSLOT, BB), 256 threads
__global__ __launch_bounds__(256) void mlp2_kernel(
    const float* __restrict__ ws_h, const float* __restrict__ stats,
    const float* __restrict__ gamma, const float* __restrict__ beta,
    const float* __restrict__ W2, const float* __restrict__ b2,
    float* __restrict__ slotn){
  int s = blockIdx.x, b = blockIdx.y, d = threadIdx.x;
  float h = ws_h[((size_t)b*NSLOT + s)*DD + d];
  int g = d >> 6;
  float s1 = stats[(b*4+g)*2+0];
  float s2 = stats[(b*4+g)*2+1];
  const float invN = 1.f/3200.f;   // 64 channels * 50 slots per group
  float mean = s1*invN;
  float var  = s2*invN - mean*mean;
  float hn = (h - mean) * rsqrtf(var + 1e-5f) * gamma[d] + beta[d];
  hn = fmaxf(hn, 0.f);
  __shared__ float hsh[DD];
  __shared__ float red[256];
  __shared__ float spo[CCC];
  hsh[d] = hn;
  __syncthreads();
  int o = d & 31, ch = d >> 5;   // 32 outputs x 8 chunks of 32
  const float4* w2q = (const float4*)(W2 + (size_t)o*DD + ch*32);
  float p = 0.f;
  #pragma unroll
  for (int q = 0; q < 8; q++){
    float4 w = w2q[q];
    const float* hp = &hsh[ch*32 + q*4];
    p = fmaf(w.x, hp[0], p);
    p = fmaf(w.y, hp[1], p);
    p = fmaf(w.z, hp[2], p);
    p = fmaf(w.w, hp[3], p);
  }
  red[d] = p;
  __syncthreads();
  if (ch == 0){
    float sp = b2[o];
    #pragma unroll
    for (int c = 0; c < 8; c++) sp += red[c*32 + o];
    spo[o] = sp;
  }
  __syncthreads();
  if (d < CCC){
    float ss = 0.f;
    #pragma unroll
    for (int o2 = 0; o2 < CCC; o2++) ss += spo[o2]*spo[o2];
    float sc = 20.f / fmaxf(sqrtf(ss), 1e-12f);   // fold 1/0.05 temperature
    slotn[((size_t)b*NSLOT + s)*CCC + d] = spo[d]*sc;
  }
}

// ---- main: per output column gather -> normalize -> 50 dots -> softmax -> store ----
// grid (NORIG/256, BB), 256 threads
__global__ __launch_bounds__(256) void main_kernel(
    const float* __restrict__ vox, const float* __restrict__ raw,
    const int* __restrict__ coords, const int* __restrict__ inv,
    const float* __restrict__ slotn, float* __restrict__ out){
  int b = blockIdx.y;
  int col = blockIdx.x*256 + threadIdx.x;
  int n = inv[b*NORIG + col];
  float r[NSLOT];
  if (n >= 0){
    const int* vc = coords + 3*((size_t)b*NVX + n);
    int c0 = vc[0], c1 = vc[1], c2 = vc[2];
    int lin = c2*(YD*ZD) + c1*ZD + c0;
    const float* vb = vox + (size_t)b*CVC*XYZ + lin;
    float f[CCC];
    #pragma unroll
    for (int c = 0; c < CVC; c++) f[c] = vb[(size_t)c*XYZ];   // 16 scattered loads
    const float4* rp = (const float4*)(raw + (size_t)CPC*((size_t)b*NVX + n));
    float4 q0 = rp[0], q1 = rp[1], q2 = rp[2], q3 = rp[3];
    f[16] = q0.x; f[17] = q0.y; f[18] = q0.z; f[19] = q0.w;
    f[20] = q1.x; f[21] = q1.y; f[22] = q1.z; f[23] = q1.w;
    f[24] = q2.x; f[25] = q2.y; f[26] = q2.z; f[27] = q2.w;
    f[28] = q3.x; f[29] = q3.y; f[30] = q3.z; f[31] = q3.w;
    float ss = 0.f;
    #pragma unroll
    for (int i = 0; i < CCC; i++) ss = fmaf(f[i], f[i], ss);
    float invn = 1.f / fmaxf(sqrtf(ss), 1e-12f);
    // slot matrix: wave-uniform addresses -> compiler can scalarize to s_load
    const float* sb = slotn + (size_t)b*NSLOT*CCC;
    float mx = -1e30f;
    #pragma unroll
    for (int k = 0; k < NSLOT; k++){
      const float4* sp = (const float4*)(sb + k*CCC);
      float acc = 0.f;
      #pragma unroll
      for (int q = 0; q < 8; q++){
        float4 v = sp[q];
        acc = fmaf(f[q*4+0], v.x, acc);
        acc = fmaf(f[q*4+1], v.y, acc);
        acc = fmaf(f[q*4+2], v.z, acc);
        acc = fmaf(f[q*4+3], v.w, acc);
      }
      r[k] = acc * invn;
      mx = fmaxf(mx, r[k]);
    }
    float sum = 0.f;
    #pragma unroll
    for (int k = 0; k < NSLOT; k++){ r[k] = __expf(r[k]-mx); sum += r[k]; }
    float rs = 1.f / sum;
    #pragma unroll
    for (int k = 0; k < NSLOT; k++) r[k] *= rs;
  } else {
    // softmax of all-zero column = 1/NSLOT
    #pragma unroll
    for (int k = 0; k < NSLOT; k++) r[k] = 0.02f;
  }
  float* op = out + (size_t)b*NORIG + col;
  #pragma unroll
  for (int k = 0; k < NSLOT; k++) op[(size_t)k*BN] = r[k];
}

extern "C" void kernel_launch(void* const* d_in, const int* in_sizes, int n_in,
                              void* d_out, int out_size, void* d_ws, size_t ws_size,
                              hipStream_t stream) {
  (void)in_sizes; (void)n_in; (void)out_size; (void)ws_size;
  const float* vox    = (const float*)d_in[0];
  const float* raw    = (const float*)d_in[1];
  const float* slot   = (const float*)d_in[2];
  const float* W1     = (const float*)d_in[3];
  const float* b1     = (const float*)d_in[4];
  const float* gamma  = (const float*)d_in[5];
  const float* beta   = (const float*)d_in[6];
  const float* W2     = (const float*)d_in[7];
  const float* b2     = (const float*)d_in[8];
  const int*   coords = (const int*)d_in[9];
  const int*   pidx   = (const int*)d_in[10];
  float*       out    = (float*)d_out;

  // workspace layout: [inv: BN ints][stats: 32 f][slotn: 4*50*32 f][ws_h: 4*50*256 f]
  int*   inv   = (int*)d_ws;
  float* stats = (float*)((char*)d_ws + BN*sizeof(int));
  float* slotn = stats + 32;
  float* ws_h  = slotn + (size_t)BB*NSLOT*CCC;

  fill_kernel   <<<dim3((unsigned)((BN + 255)/256)), 256, 0, stream>>>(inv, stats);
  scatter_kernel<<<dim3((BB*NVX + 255)/256),          256, 0, stream>>>(pidx, inv);
  mlp1_kernel   <<<dim3(NSLOT, BB),                   256, 0, stream>>>(slot, W1, b1, ws_h, stats);
  mlp2_kernel   <<<dim3(NSLOT, BB),                   256, 0, stream>>>(ws_h, stats, gamma, beta, W2, b2, slotn);
  main_kernel   <<<dim3(NORIG/256, BB),               256, 0, stream>>>(vox, raw, coords, inv, slotn, out);
}